// Round 3
// baseline (82.274 us; speedup 1.0000x reference)
//
#include <hip/hip_runtime.h>
#include <hip/hip_cooperative_groups.h>
#include <math.h>

namespace cg = cooperative_groups;

// MACE equivariant score head — single cooperative kernel.
// Dead code: Wss (d_in[5]), Wvv (d_in[7]) — s3=silu(s2) is deleted in the reference.
// out[n,m] = sum_c vraw[n,c,m] * h[n,c]
// h[n,c]   = t[n]*b[c] + sum_q feat[n,q] * M[q,c]
//   D[u,v] = dot(Wsv[u,v,:], W2)
//   F[q,v] = sum_u W1s[16+q,u] * D[u,v]
//   M[q,c] = scale * sum_v F[q,v] * W1v[c,v]
//   b[c]   = scale * sum_v (sum_u wt~[u] D[u,v]) W1v[c,v], wt~[u]=sum_{p<16} Wt[p] W1s[p,u]
//   scale  = 1/(S*V*sqrt(V))

#define S 144
#define V 128

__global__ __launch_bounds__(256) void fused_mace(
        const float* __restrict__ feat,   // [4096,512]
        const float* __restrict__ times,  // [4096,1]
        const float* __restrict__ Wt,     // [1,16]
        const float* __restrict__ W1s,    // [144,144]
        const float* __restrict__ W1v,    // [128,128]
        const float* __restrict__ Wsv,    // [144,128,128]
        const float* __restrict__ W2,     // [128,1]
        float* __restrict__ D,            // ws: 18432
        float* __restrict__ M,            // ws: 16384
        float* __restrict__ bvec,         // ws: 128
        float* __restrict__ out) {        // [4096,3]
    __shared__ float srow[4][4][V];   // 8KB   (phase 0 -> phase 3)
    __shared__ float big[V * 129];    // 66KB  (phase 2: W1v padded; phase 3: M)
    __shared__ float wrow[S];
    __shared__ float Fsh[V];

    const int tid = threadIdx.x;
    const int wave = tid >> 6;
    const int lane = tid & 63;
    const int n0 = blockIdx.x * 16 + wave * 4;

    // ---------- phase 0: issue this block's row loads (regs + LDS) ----------
    float2 va[4][3];
#pragma unroll
    for (int r = 0; r < 4; ++r) {
        const float* p = feat + (size_t)(n0 + r) * 512 + V + 6 * lane;
        va[r][0] = *(const float2*)(p + 0);
        va[r][1] = *(const float2*)(p + 2);
        va[r][2] = *(const float2*)(p + 4);
    }
    float2 sv[4];
#pragma unroll
    for (int r = 0; r < 4; ++r)
        sv[r] = *(const float2*)(feat + (size_t)(n0 + r) * 512 + 2 * lane);
    float tval[4];
#pragma unroll
    for (int r = 0; r < 4; ++r) tval[r] = times[n0 + r];

    // ---------- phase 1: D[uv] = dot(Wsv row, W2), 72 rows/block ----------
    const int uv0 = blockIdx.x * 72 + wave * 18;
    const float2 w2v = ((const float2*)W2)[lane];
    float2 a[18];
#pragma unroll
    for (int i = 0; i < 18; ++i)
        a[i] = ((const float2*)Wsv)[(size_t)(uv0 + i) * 64 + lane];

    // park scalars in LDS while the Wsv loads are in flight
#pragma unroll
    for (int r = 0; r < 4; ++r)
        *(float2*)&srow[wave][r][2 * lane] = sv[r];

#pragma unroll
    for (int i = 0; i < 18; ++i) {
        float acc = a[i].x * w2v.x + a[i].y * w2v.y;
#pragma unroll
        for (int off = 1; off < 64; off <<= 1)
            acc += __shfl_xor(acc, off, 64);
        if (lane == 0) D[uv0 + i] = acc;
    }

    cg::this_grid().sync();

    // ---------- phase 2: rows of M (blocks 0..127) and b (block 128) ----------
    if (blockIdx.x < 129) {
        const int q = blockIdx.x;
        for (int i = tid; i < V * V; i += 256)
            big[(i >> 7) * 129 + (i & 127)] = W1v[i];
        if (tid < S) {
            if (q < V) {
                wrow[tid] = W1s[(16 + q) * S + tid];
            } else {
                float acc = 0.f;
#pragma unroll
                for (int p = 0; p < 16; ++p)
                    acc = fmaf(Wt[p], W1s[p * S + tid], acc);
                wrow[tid] = acc;
            }
        }
        __syncthreads();
        if (tid < V) {
            float a0 = 0.f, a1 = 0.f, a2 = 0.f, a3 = 0.f;
#pragma unroll 9
            for (int u = 0; u < S; u += 4) {
                a0 = fmaf(wrow[u + 0], D[(u + 0) * V + tid], a0);
                a1 = fmaf(wrow[u + 1], D[(u + 1) * V + tid], a1);
                a2 = fmaf(wrow[u + 2], D[(u + 2) * V + tid], a2);
                a3 = fmaf(wrow[u + 3], D[(u + 3) * V + tid], a3);
            }
            Fsh[tid] = (a0 + a1) + (a2 + a3);
        }
        __syncthreads();
        if (tid < V) {
            const float scale = 1.0f / (144.0f * 128.0f * sqrtf(128.0f));
            float m0 = 0.f, m1 = 0.f;
#pragma unroll 16
            for (int v = 0; v < V; v += 2) {
                m0 = fmaf(Fsh[v + 0], big[tid * 129 + v + 0], m0);
                m1 = fmaf(Fsh[v + 1], big[tid * 129 + v + 1], m1);
            }
            const float r = (m0 + m1) * scale;
            if (q < V) M[q * V + tid] = r;
            else       bvec[tid] = r;
        }
    }

    cg::this_grid().sync();

    // ---------- phase 3: h = t*b + s.M (M broadcast in LDS), then epilogue ----------
    {
        const float4* src = (const float4*)M;
        float4* dst = (float4*)big;   // reuse as Msh, stride V
#pragma unroll
        for (int i = 0; i < 16; ++i)
            dst[tid + 256 * i] = src[tid + 256 * i];
    }
    const float2 b2 = *(const float2*)(bvec + 2 * lane);
    __syncthreads();

    float h0[4], h1[4];
#pragma unroll
    for (int r = 0; r < 4; ++r) {
        h0[r] = tval[r] * b2.x;
        h1[r] = tval[r] * b2.y;
    }

#pragma unroll 4
    for (int q4 = 0; q4 < V / 4; ++q4) {
        const float4 s0 = *(const float4*)&srow[wave][0][q4 * 4];
        const float4 s1 = *(const float4*)&srow[wave][1][q4 * 4];
        const float4 s2 = *(const float4*)&srow[wave][2][q4 * 4];
        const float4 s3 = *(const float4*)&srow[wave][3][q4 * 4];
        const float se[4][4] = {{s0.x, s0.y, s0.z, s0.w},
                                {s1.x, s1.y, s1.z, s1.w},
                                {s2.x, s2.y, s2.z, s2.w},
                                {s3.x, s3.y, s3.z, s3.w}};
#pragma unroll
        for (int j = 0; j < 4; ++j) {
            const float2 m2 = *(const float2*)&big[(q4 * 4 + j) * V + 2 * lane];
#pragma unroll
            for (int r = 0; r < 4; ++r) {
                h0[r] = fmaf(se[r][j], m2.x, h0[r]);
                h1[r] = fmaf(se[r][j], m2.y, h1[r]);
            }
        }
    }

    // epilogue: lane l holds channels c=2l (va[0].x, va[0].y, va[1].x)
    // and c=2l+1 (va[1].y, va[2].x, va[2].y)
#pragma unroll
    for (int r = 0; r < 4; ++r) {
        float pm0 = va[r][0].x * h0[r] + va[r][1].y * h1[r];
        float pm1 = va[r][0].y * h0[r] + va[r][2].x * h1[r];
        float pm2 = va[r][1].x * h0[r] + va[r][2].y * h1[r];
#pragma unroll
        for (int off = 1; off < 64; off <<= 1) {
            pm0 += __shfl_xor(pm0, off, 64);
            pm1 += __shfl_xor(pm1, off, 64);
            pm2 += __shfl_xor(pm2, off, 64);
        }
        if (lane == 0) {
            out[(n0 + r) * 3 + 0] = pm0;
            out[(n0 + r) * 3 + 1] = pm1;
            out[(n0 + r) * 3 + 2] = pm2;
        }
    }
}

extern "C" void kernel_launch(void* const* d_in, const int* in_sizes, int n_in,
                              void* d_out, int out_size, void* d_ws, size_t ws_size,
                              hipStream_t stream) {
    const float* feat  = (const float*)d_in[0];
    const float* times = (const float*)d_in[1];
    const float* Wt    = (const float*)d_in[2];
    const float* W1s   = (const float*)d_in[3];
    const float* W1v   = (const float*)d_in[4];
    // d_in[5] = Wss  -- dead path
    const float* Wsv   = (const float*)d_in[6];
    // d_in[7] = Wvv  -- dead path
    const float* W2    = (const float*)d_in[8];

    float* ws   = (float*)d_ws;
    float* D    = ws;            // 18432 f32
    float* M    = ws + 18432;    // 16384 f32
    float* bv   = ws + 34816;    // 128 f32
    float* outp = (float*)d_out;

    void* args[] = {(void*)&feat, (void*)&times, (void*)&Wt, (void*)&W1s,
                    (void*)&W1v,  (void*)&Wsv,   (void*)&W2, (void*)&D,
                    (void*)&M,    (void*)&bv,    (void*)&outp};
    hipLaunchCooperativeKernel((const void*)fused_mace, dim3(256), dim3(256),
                               args, 0, stream);
}

// Round 4
// 36.106 us; speedup vs baseline: 2.2787x; 2.2787x over previous
//
#include <hip/hip_runtime.h>
#include <math.h>

// MACE equivariant score head, restructured (3 kernels).
// Dead code: Wss (d_in[5]), Wvv (d_in[7]) — s3=silu(s2) is deleted in the reference.
// out[n,m] = sum_c vraw[n,c,m] * h[n,c]
// h[n,c]   = t[n]*b[c] + sum_q feat[n,q] * M[q,c]
// Precompute:
//   D[u,v] = dot(Wsv[u,v,:], W2)
//   F[v]   = sum_u wrow[u] * D[u,v]        (wrow = W1s row 16+q, or Wt-combo for b)
//   M[q,c] = scale * sum_v F[v] * W1v[c,v]
//   scale  = 1/(S*V*sqrt(V))  (all fan-in norms folded)

#define S 144
#define V 128

__device__ inline float rdlane(float v, int l) {
    return __int_as_float(__builtin_amdgcn_readlane(__float_as_int(v), l));
}

// ---------------- K1: D[u*V+v] = dot(Wsv[u,v,:], W2) ----------------
__global__ __launch_bounds__(256) void k1_D(const float* __restrict__ Wsv,
                                            const float* __restrict__ W2,
                                            float* __restrict__ D) {
    const int wave = threadIdx.x >> 6;
    const int lane = threadIdx.x & 63;
    const int uv = blockIdx.x * 4 + wave;       // grid 4608 -> uv in [0,18432)
    const float2* src = (const float2*)Wsv + (size_t)uv * 64;
    const float2* w2 = (const float2*)W2;
    float2 a = src[lane];
    float2 w = w2[lane];
    float acc = a.x * w.x + a.y * w.y;
#pragma unroll
    for (int off = 1; off < 64; off <<= 1)
        acc += __shfl_xor(acc, off, 64);
    if (lane == 0) D[uv] = acc;
}

// ---------------- K23: per-block row of M (or b) ----------------
// block q in [0,129): q<128 -> M row q; q==128 -> b.
// D and W1v staged in LDS (coalesced); F-reduction split over 4 waves.
__global__ __launch_bounds__(256, 1) void k23_Mb(const float* __restrict__ D,
                                                 const float* __restrict__ W1s,
                                                 const float* __restrict__ W1v,
                                                 const float* __restrict__ Wt,
                                                 float* __restrict__ M,
                                                 float* __restrict__ b) {
    __shared__ float Dlds[S * V];      // 72 KB
    __shared__ float w1v[V * 129];     // 66 KB, +1 pad -> row reads 2-way-free
    __shared__ float wrow[S];
    __shared__ float Fpart[4][V];      // 2 KB
    __shared__ float Fsh[V];
    const int tid = threadIdx.x;
    const int q = blockIdx.x;

    // stage D (72KB) as float4, coalesced
    {
        const float4* D4 = (const float4*)D;
        float4* Dl4 = (float4*)Dlds;
        for (int i = tid; i < S * V / 4; i += 256)
            Dl4[i] = D4[i];
    }
    // stage W1v padded (scalar stores; global read coalesced)
    for (int i = tid; i < V * V; i += 256)
        w1v[(i >> 7) * 129 + (i & 127)] = W1v[i];
    // wrow
    if (tid < S) {
        if (q < V) {
            wrow[tid] = W1s[(16 + q) * S + tid];
        } else {
            float acc = 0.f;
#pragma unroll
            for (int p = 0; p < 16; ++p)
                acc = fmaf(Wt[p], W1s[p * S + tid], acc);
            wrow[tid] = acc;
        }
    }
    __syncthreads();

    // F[v] = sum_u wrow[u]*D[u,v]; wave w covers u in [36w, 36w+36), lane t -> v=2t,2t+1
    {
        const int w = tid >> 6, t = tid & 63;
        float fx = 0.f, fy = 0.f;
#pragma unroll 6
        for (int u = 36 * w; u < 36 * w + 36; ++u) {
            const float wr = wrow[u];
            const float2 dv = *(const float2*)&Dlds[u * V + 2 * t];
            fx = fmaf(wr, dv.x, fx);
            fy = fmaf(wr, dv.y, fy);
        }
        Fpart[w][2 * t + 0] = fx;
        Fpart[w][2 * t + 1] = fy;
    }
    __syncthreads();
    if (tid < V)
        Fsh[tid] = (Fpart[0][tid] + Fpart[1][tid]) + (Fpart[2][tid] + Fpart[3][tid]);
    __syncthreads();

    // out[c] = scale * sum_v Fsh[v] * W1v[c,v],  c = tid (<128)
    if (tid < V) {
        const float scale = 1.0f / (144.0f * 128.0f * sqrtf(128.0f));
        float m0 = 0.f, m1 = 0.f, m2 = 0.f, m3 = 0.f;
#pragma unroll 8
        for (int v = 0; v < V; v += 4) {
            m0 = fmaf(Fsh[v + 0], w1v[tid * 129 + v + 0], m0);
            m1 = fmaf(Fsh[v + 1], w1v[tid * 129 + v + 1], m1);
            m2 = fmaf(Fsh[v + 2], w1v[tid * 129 + v + 2], m2);
            m3 = fmaf(Fsh[v + 3], w1v[tid * 129 + v + 3], m3);
        }
        const float r = ((m0 + m1) + (m2 + m3)) * scale;
        if (q < V) M[q * V + tid] = r;
        else       b[tid] = r;
    }
}

// ---------------- K4: main streaming kernel ----------------
// 256 blocks x 256 thr (4 waves), 16 rows/block, 4 rows/wave.
// s stays in registers (lane l holds q=2l,2l+1); broadcast via v_readlane (VALU),
// so LDS carries only the M float2 reads (2-way aliasing = free).
__global__ __launch_bounds__(256) void k4_main(const float* __restrict__ feat,
                                               const float* __restrict__ times,
                                               const float* __restrict__ Mg,
                                               const float* __restrict__ bg,
                                               float* __restrict__ out) {
    __shared__ float Msh[V * V];          // 64 KB
    const int tid = threadIdx.x;
    const int wave = tid >> 6;
    const int lane = tid & 63;
    const int n0 = blockIdx.x * 16 + wave * 4;

    // vector part of this wave's 4 rows -> registers (lane owns channels 2l, 2l+1)
    float2 va[4][3];
#pragma unroll
    for (int r = 0; r < 4; ++r) {
        const float* p = feat + (size_t)(n0 + r) * 512 + V + 6 * lane;
        va[r][0] = *(const float2*)(p + 0);
        va[r][1] = *(const float2*)(p + 2);
        va[r][2] = *(const float2*)(p + 4);
    }
    // scalar part -> registers: lane l holds s[r][2l], s[r][2l+1]
    float2 sv[4];
#pragma unroll
    for (int r = 0; r < 4; ++r)
        sv[r] = *(const float2*)(feat + (size_t)(n0 + r) * 512 + 2 * lane);

    // cooperative M load: 16384 f32 = 4096 float4 / 256 thr
    {
        const float4* src = (const float4*)Mg;
        float4* dst = (float4*)Msh;
#pragma unroll
        for (int i = 0; i < 16; ++i)
            dst[tid + 256 * i] = src[tid + 256 * i];
    }
    const float2 b2 = *(const float2*)(bg + 2 * lane);
    float h0[4], h1[4];
#pragma unroll
    for (int r = 0; r < 4; ++r) {
        const float t = times[n0 + r];
        h0[r] = t * b2.x;
        h1[r] = t * b2.y;
    }
    __syncthreads();

    // h[r, 2l / 2l+1] += sum_q s[r][q] * M[q, 2l / 2l+1]
    for (int q0 = 0; q0 < V; q0 += 8) {
#pragma unroll
        for (int j = 0; j < 8; ++j) {
            const int q = q0 + j;
            const float2 m2 = *(const float2*)&Msh[q * V + 2 * lane];
            const int src_lane = q >> 1;
#pragma unroll
            for (int r = 0; r < 4; ++r) {
                const float sq = rdlane((j & 1) ? sv[r].y : sv[r].x, src_lane);
                h0[r] = fmaf(sq, m2.x, h0[r]);
                h1[r] = fmaf(sq, m2.y, h1[r]);
            }
        }
    }

    // epilogue: out[n,m] = sum_c vraw[c,m]*h[c]; lane l holds c=2l (va[0].x,va[0].y,va[1].x)
    // and c=2l+1 (va[1].y,va[2].x,va[2].y)
#pragma unroll
    for (int r = 0; r < 4; ++r) {
        float pm0 = va[r][0].x * h0[r] + va[r][1].y * h1[r];
        float pm1 = va[r][0].y * h0[r] + va[r][2].x * h1[r];
        float pm2 = va[r][1].x * h0[r] + va[r][2].y * h1[r];
#pragma unroll
        for (int off = 1; off < 64; off <<= 1) {
            pm0 += __shfl_xor(pm0, off, 64);
            pm1 += __shfl_xor(pm1, off, 64);
            pm2 += __shfl_xor(pm2, off, 64);
        }
        if (lane == 0) {
            out[(n0 + r) * 3 + 0] = pm0;
            out[(n0 + r) * 3 + 1] = pm1;
            out[(n0 + r) * 3 + 2] = pm2;
        }
    }
}

extern "C" void kernel_launch(void* const* d_in, const int* in_sizes, int n_in,
                              void* d_out, int out_size, void* d_ws, size_t ws_size,
                              hipStream_t stream) {
    const float* feat  = (const float*)d_in[0];  // [4096, 512]
    const float* times = (const float*)d_in[1];  // [4096, 1]
    const float* Wt    = (const float*)d_in[2];  // [1,16]
    const float* W1s   = (const float*)d_in[3];  // [144,144]
    const float* W1v   = (const float*)d_in[4];  // [128,128]
    // d_in[5] = Wss  -- dead path
    const float* Wsv   = (const float*)d_in[6];  // [144,128,128]
    // d_in[7] = Wvv  -- dead path
    const float* W2    = (const float*)d_in[8];  // [128,1]

    float* ws = (float*)d_ws;
    float* D  = ws;            // 18432 f32
    float* M  = ws + 18432;    // 16384 f32
    float* b  = ws + 34816;    // 128 f32

    k1_D<<<dim3(4608), dim3(256), 0, stream>>>(Wsv, W2, D);
    k23_Mb<<<dim3(129), dim3(256), 0, stream>>>(D, W1s, W1v, Wt, M, b);
    k4_main<<<dim3(256), dim3(256), 0, stream>>>(feat, times, M, b, (float*)d_out);
}

// Round 5
// 22.239 us; speedup vs baseline: 3.6995x; 1.6235x over previous
//
#include <hip/hip_runtime.h>
#include <math.h>

// MACE equivariant score head, restructured (3 kernels).
// Dead code: Wss (d_in[5]), Wvv (d_in[7]) — s3=silu(s2) is deleted in the reference.
// out[n,m] = sum_c vraw[n,c,m] * h[n,c]
// h[n,c]   = t[n]*b[c] + sum_q feat[n,q] * M[q,c]
// Precompute:
//   D[u,v] = dot(Wsv[u,v,:], W2)
//   F[v]   = sum_u wrow[u] * D[u,v]        (wrow = W1s row 16+q, or Wt-combo for b)
//   M[q,c] = scale * sum_v F[v] * W1v[c,v]
//   scale  = 1/(S*V*sqrt(V))  (all fan-in norms folded)

#define S 144
#define V 128

// ---------------- K1: D[u*V+v] = dot(Wsv[u,v,:], W2) ----------------
__global__ __launch_bounds__(256) void k1_D(const float* __restrict__ Wsv,
                                            const float* __restrict__ W2,
                                            float* __restrict__ D) {
    const int wave = threadIdx.x >> 6;
    const int lane = threadIdx.x & 63;
    const int uv = blockIdx.x * 4 + wave;       // grid 4608 -> uv in [0,18432)
    const float2* src = (const float2*)Wsv + (size_t)uv * 64;
    const float2* w2 = (const float2*)W2;
    float2 a = src[lane];
    float2 w = w2[lane];
    float acc = a.x * w.x + a.y * w.y;
#pragma unroll
    for (int off = 1; off < 64; off <<= 1)
        acc += __shfl_xor(acc, off, 64);
    if (lane == 0) D[uv] = acc;
}

// ---------------- K23: per-block row of M (or b) ----------------
// block q in [0,129): q<128 -> M row q; q==128 -> b.
// W1v staged in LDS (multi-use, padded); D read directly from L2 (single-use).
__global__ __launch_bounds__(256) void k23_Mb(const float* __restrict__ D,
                                              const float* __restrict__ W1s,
                                              const float* __restrict__ W1v,
                                              const float* __restrict__ Wt,
                                              float* __restrict__ M,
                                              float* __restrict__ b) {
    __shared__ float w1v[V * 129];     // 66 KB, +1 pad
    __shared__ float wrow[S];
    __shared__ float Fpart[4][V];
    __shared__ float Fsh[V];
    const int tid = threadIdx.x;
    const int q = blockIdx.x;

    // stage W1v padded: float4 global loads, scalar LDS stores
    {
        const float4* W1v4 = (const float4*)W1v;
        for (int i = tid; i < V * V / 4; i += 256) {
            const float4 t = W1v4[i];
            const int base = i * 4;
            float* dst = &w1v[(base >> 7) * 129 + (base & 127)];
            dst[0] = t.x; dst[1] = t.y; dst[2] = t.z; dst[3] = t.w;
        }
    }
    if (tid < S) {
        if (q < V) {
            wrow[tid] = W1s[(16 + q) * S + tid];
        } else {
            float acc = 0.f;
#pragma unroll
            for (int p = 0; p < 16; ++p)
                acc = fmaf(Wt[p], W1s[p * S + tid], acc);
            wrow[tid] = acc;
        }
    }
    __syncthreads();

    // F[v] = sum_u wrow[u]*D[u,v]; wave w covers u in [36w,36w+36), lane t -> v=2t,2t+1
    {
        const int w = tid >> 6, t = tid & 63;
        float fx = 0.f, fy = 0.f;
#pragma unroll 6
        for (int u = 36 * w; u < 36 * w + 36; ++u) {
            const float wr = wrow[u];
            const float2 dv = *(const float2*)&D[u * V + 2 * t];
            fx = fmaf(wr, dv.x, fx);
            fy = fmaf(wr, dv.y, fy);
        }
        Fpart[w][2 * t + 0] = fx;
        Fpart[w][2 * t + 1] = fy;
    }
    __syncthreads();
    if (tid < V)
        Fsh[tid] = (Fpart[0][tid] + Fpart[1][tid]) + (Fpart[2][tid] + Fpart[3][tid]);
    __syncthreads();

    // out[c] = scale * sum_v Fsh[v] * W1v[c,v],  c = tid (<128)
    if (tid < V) {
        const float scale = 1.0f / (144.0f * 128.0f * sqrtf(128.0f));
        float m0 = 0.f, m1 = 0.f, m2 = 0.f, m3 = 0.f;
#pragma unroll 8
        for (int v = 0; v < V; v += 4) {
            m0 = fmaf(Fsh[v + 0], w1v[tid * 129 + v + 0], m0);
            m1 = fmaf(Fsh[v + 1], w1v[tid * 129 + v + 1], m1);
            m2 = fmaf(Fsh[v + 2], w1v[tid * 129 + v + 2], m2);
            m3 = fmaf(Fsh[v + 3], w1v[tid * 129 + v + 3], m3);
        }
        const float r = ((m0 + m1) + (m2 + m3)) * scale;
        if (q < V) M[q * V + tid] = r;
        else       b[tid] = r;
    }
}

// ---------------- K4: main streaming kernel ----------------
// 512 blocks x 256 thr (4 waves), 8 rows/block, 2 rows/wave.
// LDS = Msh 64KB + srow 4KB = 68KB -> 2 blocks/CU, 8 waves/CU.
__global__ __launch_bounds__(256) void k4_main(const float* __restrict__ feat,
                                               const float* __restrict__ times,
                                               const float* __restrict__ Mg,
                                               const float* __restrict__ bg,
                                               float* __restrict__ out) {
    __shared__ float Msh[V * V];          // 64 KB
    __shared__ float srow[4][2][V];       // 4 KB
    const int tid = threadIdx.x;
    const int wave = tid >> 6;
    const int lane = tid & 63;
    const int n0 = blockIdx.x * 8 + wave * 2;

    // vector part of this wave's 2 rows -> registers (lane owns channels 2l, 2l+1)
    float2 va[2][3];
#pragma unroll
    for (int r = 0; r < 2; ++r) {
        const float* p = feat + (size_t)(n0 + r) * 512 + V + 6 * lane;
        va[r][0] = *(const float2*)(p + 0);
        va[r][1] = *(const float2*)(p + 2);
        va[r][2] = *(const float2*)(p + 4);
    }
    // scalar part -> LDS (broadcast source for the GEMV)
#pragma unroll
    for (int r = 0; r < 2; ++r) {
        float2 sv = *(const float2*)(feat + (size_t)(n0 + r) * 512 + 2 * lane);
        *(float2*)&srow[wave][r][2 * lane] = sv;
    }
    // cooperative M load: 16384 f32 = 4096 float4 / 256 thr
    {
        const float4* src = (const float4*)Mg;
        float4* dst = (float4*)Msh;
#pragma unroll
        for (int i = 0; i < 16; ++i)
            dst[tid + 256 * i] = src[tid + 256 * i];
    }
    const float2 b2 = *(const float2*)(bg + 2 * lane);
    float h0[2], h1[2];
#pragma unroll
    for (int r = 0; r < 2; ++r) {
        const float t = times[n0 + r];
        h0[r] = t * b2.x;
        h1[r] = t * b2.y;
    }
    __syncthreads();

    // h[r, 2l / 2l+1] += sum_q srow[r][q] * M[q, 2l / 2l+1]
#pragma unroll 4
    for (int q4 = 0; q4 < V / 4; ++q4) {
        const float4 s0 = *(const float4*)&srow[wave][0][q4 * 4];
        const float4 s1 = *(const float4*)&srow[wave][1][q4 * 4];
        const float se[2][4] = {{s0.x, s0.y, s0.z, s0.w},
                                {s1.x, s1.y, s1.z, s1.w}};
#pragma unroll
        for (int j = 0; j < 4; ++j) {
            const float2 m2 = *(const float2*)&Msh[(q4 * 4 + j) * V + 2 * lane];
#pragma unroll
            for (int r = 0; r < 2; ++r) {
                h0[r] = fmaf(se[r][j], m2.x, h0[r]);
                h1[r] = fmaf(se[r][j], m2.y, h1[r]);
            }
        }
    }

    // epilogue: lane l holds channels c=2l (va[0].x, va[0].y, va[1].x)
    // and c=2l+1 (va[1].y, va[2].x, va[2].y)
#pragma unroll
    for (int r = 0; r < 2; ++r) {
        float pm0 = va[r][0].x * h0[r] + va[r][1].y * h1[r];
        float pm1 = va[r][0].y * h0[r] + va[r][2].x * h1[r];
        float pm2 = va[r][1].x * h0[r] + va[r][2].y * h1[r];
#pragma unroll
        for (int off = 1; off < 64; off <<= 1) {
            pm0 += __shfl_xor(pm0, off, 64);
            pm1 += __shfl_xor(pm1, off, 64);
            pm2 += __shfl_xor(pm2, off, 64);
        }
        if (lane == 0) {
            out[(n0 + r) * 3 + 0] = pm0;
            out[(n0 + r) * 3 + 1] = pm1;
            out[(n0 + r) * 3 + 2] = pm2;
        }
    }
}

extern "C" void kernel_launch(void* const* d_in, const int* in_sizes, int n_in,
                              void* d_out, int out_size, void* d_ws, size_t ws_size,
                              hipStream_t stream) {
    const float* feat  = (const float*)d_in[0];  // [4096, 512]
    const float* times = (const float*)d_in[1];  // [4096, 1]
    const float* Wt    = (const float*)d_in[2];  // [1,16]
    const float* W1s   = (const float*)d_in[3];  // [144,144]
    const float* W1v   = (const float*)d_in[4];  // [128,128]
    // d_in[5] = Wss  -- dead path
    const float* Wsv   = (const float*)d_in[6];  // [144,128,128]
    // d_in[7] = Wvv  -- dead path
    const float* W2    = (const float*)d_in[8];  // [128,1]

    float* ws = (float*)d_ws;
    float* D  = ws;            // 18432 f32
    float* M  = ws + 18432;    // 16384 f32
    float* b  = ws + 34816;    // 128 f32

    k1_D<<<dim3(4608), dim3(256), 0, stream>>>(Wsv, W2, D);
    k23_Mb<<<dim3(129), dim3(256), 0, stream>>>(D, W1s, W1v, Wt, M, b);
    k4_main<<<dim3(512), dim3(256), 0, stream>>>(feat, times, M, b, (float*)d_out);
}